// Round 5
// baseline (648.173 us; speedup 1.0000x reference)
//
#include <hip/hip_runtime.h>

#define BB 8
#define NN 2048
#define FIN0 16
#define EE 64
#define HH 4
#define DD 16
#define HIDN 128
#define AA 4

// ---------------- adjacency -> blocked bitmask, TRANSPOSED: mbT[b][kblk][q] ----------------
__global__ __launch_bounds__(256) void k_mask(const float* __restrict__ adj, unsigned long long* __restrict__ mbT) {
    const int ITER = 32;
    for (int it = 0; it < ITER; it++) {
        long long idx = ((long long)blockIdx.x * ITER + it) * 256 + threadIdx.x;  // b*N*N + r*N + k
        int k = (int)(idx & (NN - 1));
        int r = (int)((idx >> 11) & (NN - 1));
        int b = (int)(idx >> 22);
        float a = adj[idx];
        bool blocked = (a == 0.0f) && (k != r);
        unsigned long long m = __ballot(blocked);
        if ((threadIdx.x & 63) == 0) mbT[((long long)b * 32 + (k >> 6)) * NN + r] = m;
    }
}

// ---------------- fold weights: CW = {wq,wk,wv}@in_w (Q cols pre-scaled), WO = mha_ow@op_w ----------------
#define QSCALE 0.36067376022224085f   // 0.25 * log2(e)
__device__ __forceinline__ float sfeat(int f) {
    return (f == 4 || f == 14 || f == 15) ? 1.0f : ((f == 5) ? (1.0f / 300.0f) : 0.02f);
}
__global__ __launch_bounds__(256) void k_wcomb(
        const float* __restrict__ wq0, const float* __restrict__ wk0, const float* __restrict__ wv0,
        const float* __restrict__ inw0, const float* __restrict__ inb0,
        const float* __restrict__ mow0, const float* __restrict__ mob0,
        const float* __restrict__ opw0, const float* __restrict__ opb0,
        const float* __restrict__ wq1, const float* __restrict__ wk1, const float* __restrict__ wv1,
        const float* __restrict__ inw1, const float* __restrict__ inb1,
        const float* __restrict__ mow1, const float* __restrict__ mob1,
        const float* __restrict__ opw1, const float* __restrict__ opb1,
        float* __restrict__ CW0, float* __restrict__ WO0, float* __restrict__ bO0, float* __restrict__ bQ0,
        float* __restrict__ CW1, float* __restrict__ WO1, float* __restrict__ bO1, float* __restrict__ bQ1) {
    int ly = blockIdx.y;
    int fin = ly ? EE : FIN0;
    const float* wq = ly ? wq1 : wq0; const float* wk = ly ? wk1 : wk0; const float* wv = ly ? wv1 : wv0;
    const float* inw = ly ? inw1 : inw0; const float* inb = ly ? inb1 : inb0;
    const float* mow = ly ? mow1 : mow0; const float* mob = ly ? mob1 : mob0;
    const float* opw = ly ? opw1 : opw0; const float* opb = ly ? opb1 : opb0;
    float* CW = ly ? CW1 : CW0; float* WO = ly ? WO1 : WO0;
    float* bO = ly ? bO1 : bO0; float* bQ = ly ? bQ1 : bQ0;

    int t = blockIdx.x * 256 + threadIdx.x;
    int t1 = fin * 192;
    int t2 = t1 + 4096;
    int t3 = t2 + 64;
    int t4 = t3 + 192;
    if (t < t1) {
        int f = t / 192, j = t % 192;
        const float* w = (j < 64) ? wq : ((j < 128) ? wk : wv);
        float acc = 0.f;
        for (int kk = 0; kk < 64; kk++) acc += w[f * 64 + kk] * inw[kk * 192 + j];
        if (j < 64) acc *= QSCALE;
        if (ly == 0) acc *= sfeat(f);
        CW[t] = acc;
    } else if (t < t2) {
        int u = t - t1; int i = u >> 6, j = u & 63;
        float acc = 0.f;
        for (int kk = 0; kk < 64; kk++) acc += mow[i * 64 + kk] * opw[kk * 64 + j];
        WO[u] = acc;
    } else if (t < t3) {
        int j = t - t2;
        float acc = opb[j];
        for (int kk = 0; kk < 64; kk++) acc += mob[kk] * opw[kk * 64 + j];
        bO[j] = acc;
    } else if (t < t4) {
        int j = t - t3;
        bQ[j] = inb[j] * ((j < 64) ? QSCALE : 1.0f);
    }
}

// ---------------- fused QKV projection (layer 0): X[B*N][fin] @ CW + bQ -> Q,K,V [B][H][N][D] ----------------
template <int FINP>
__global__ __launch_bounds__(256) void k_qkv(const float* __restrict__ X, const float* __restrict__ CW,
                                             const float* __restrict__ bQ,
                                             float* __restrict__ Q, float* __restrict__ K, float* __restrict__ V) {
    int lane = threadIdx.x & 63;
    int quarter = threadIdx.x >> 6;
    int row = blockIdx.x * 64 + lane;
    int b = row >> 11, n = row & (NN - 1);
    float xr[FINP];
    const float4* xp = (const float4*)(X + (long long)row * FINP);
#pragma unroll
    for (int i = 0; i < FINP / 4; i++) {
        float4 v = xp[i];
        xr[4 * i] = v.x; xr[4 * i + 1] = v.y; xr[4 * i + 2] = v.z; xr[4 * i + 3] = v.w;
    }
    for (int jq = 0; jq < 12; jq++) {
        int j = quarter * 48 + jq * 4;
        float4 acc = *(const float4*)(bQ + j);
#pragma unroll
        for (int f = 0; f < FINP; f++) {
            float4 w = *(const float4*)(CW + f * 192 + j);
            acc.x = fmaf(xr[f], w.x, acc.x);
            acc.y = fmaf(xr[f], w.y, acc.y);
            acc.z = fmaf(xr[f], w.z, acc.z);
            acc.w = fmaf(xr[f], w.w, acc.w);
        }
        int which = j >> 6, c = j & 63, h = c >> 4, d = c & 15;
        float* dst = (which == 0) ? Q : ((which == 1) ? K : V);
        *(float4*)(dst + (((long long)(b * HH + h) * NN + n) * DD + d)) = acc;
    }
}

// ---------------- attention v5: NO LDS staging — K/V read directly from global ----------------
// All 64 lanes of a wave read the SAME K/V row per kk (wave-uniform address -> one 64B
// segment broadcast from L1; VMEM pipe, not LDS). 1-row register double-buffer hides L2
// latency (~200cyc) behind one inner iteration (~580 SIMD-cyc at 2 waves/SIMD). LDS is used
// only for the cross-wave epilogue reduction; no barriers in the main loop.
__global__ __launch_bounds__(512, 2) void k_attn(const float* __restrict__ Q, const float* __restrict__ K,
                                                 const float* __restrict__ V,
                                                 const unsigned long long* __restrict__ mbT,
                                                 float* __restrict__ O) {
    __shared__ float smem[8 * 4 * 64 * 17];            // epilogue reduction only
    int lane = threadIdx.x & 63;
    int w = threadIdx.x >> 6;                          // k-eighth owner (256 rows)
    int qb = blockIdx.x, h = blockIdx.y, b = blockIdx.z;
    int qbase = qb * 256;

    const float* Qbh = Q + (long long)(b * HH + h) * NN * DD;
    const float* Kb  = K + (long long)(b * HH + h) * NN * DD;
    const float* Vb  = V + (long long)(b * HH + h) * NN * DD;
    const unsigned long long* mrow = mbT + (long long)b * 32 * NN;

    float4 qf[4][4];
#pragma unroll
    for (int rq = 0; rq < 4; rq++) {
        const float4* qp = (const float4*)(Qbh + (long long)(qbase + rq * 64 + lane) * DD);
#pragma unroll
        for (int j = 0; j < 4; j++) qf[rq][j] = qp[j];
    }
    float4 oacc[4][4];
#pragma unroll
    for (int rq = 0; rq < 4; rq++)
#pragma unroll
        for (int j = 0; j < 4; j++) oacc[rq][j] = make_float4(0.f, 0.f, 0.f, 0.f);
    float lsum[4] = {0.f, 0.f, 0.f, 0.f};

    // this wave's contiguous 256-row k-range
    const float4* kp = (const float4*)(Kb + (long long)(w * 256) * DD);
    const float4* vp = (const float4*)(Vb + (long long)(w * 256) * DD);

    // register double-buffer: row 0 preloaded; row idx+1 loads during row idx compute.
    float4 kc[4], vc[4];
#pragma unroll
    for (int i = 0; i < 4; i++) { kc[i] = kp[i]; vc[i] = vp[i]; }
    unsigned long long mwpre[4];
#pragma unroll
    for (int rq = 0; rq < 4; rq++) mwpre[rq] = mrow[(long long)(w * 4) * NN + qbase + rq * 64 + lane];

    for (int c = 0; c < 4; c++) {
        unsigned long long mw[4];
#pragma unroll
        for (int rq = 0; rq < 4; rq++) mw[rq] = mwpre[rq];
        // prefetch next chunk's mask words (last iteration overreads into the adjacent
        // workspace buffer — allocated, never used)
        {
            int kblkn = w * 4 + c + 1;
#pragma unroll
            for (int rq = 0; rq < 4; rq++) mwpre[rq] = mrow[(long long)kblkn * NN + qbase + rq * 64 + lane];
        }
#pragma unroll 4
        for (int kk = 0; kk < 64; kk++) {
            int idx = c * 64 + kk;
            // issue next row's loads (overreads 1 row past the wave's range on the last
            // iteration — lands in the next ws buffer, never used)
            float4 kn[4], vn[4];
#pragma unroll
            for (int i = 0; i < 4; i++) { kn[i] = kp[(idx + 1) * 4 + i]; vn[i] = vp[(idx + 1) * 4 + i]; }
            float4 k0 = kc[0], k1 = kc[1], k2 = kc[2], k3 = kc[3];
            float e[4];
#pragma unroll
            for (int rq = 0; rq < 4; rq++) {
                float4 a0 = qf[rq][0], a1 = qf[rq][1], a2 = qf[rq][2], a3 = qf[rq][3];
                float sA = a0.x * k0.x;
                sA = fmaf(a0.y, k0.y, sA); sA = fmaf(a0.z, k0.z, sA); sA = fmaf(a0.w, k0.w, sA);
                sA = fmaf(a1.x, k1.x, sA); sA = fmaf(a1.y, k1.y, sA); sA = fmaf(a1.z, k1.z, sA); sA = fmaf(a1.w, k1.w, sA);
                float sB = a2.x * k2.x;
                sB = fmaf(a2.y, k2.y, sB); sB = fmaf(a2.z, k2.z, sB); sB = fmaf(a2.w, k2.w, sB);
                sB = fmaf(a3.x, k3.x, sB); sB = fmaf(a3.y, k3.y, sB); sB = fmaf(a3.z, k3.z, sB); sB = fmaf(a3.w, k3.w, sB);
                float ee = __builtin_amdgcn_exp2f(sA + sB);     // softmax scale folded into Q
                e[rq] = ((mw[rq] >> kk) & 1ULL) ? 0.f : ee;
                lsum[rq] += e[rq];
            }
            float4 v0 = vc[0], v1 = vc[1], v2 = vc[2], v3 = vc[3];
#pragma unroll
            for (int rq = 0; rq < 4; rq++) {
                float ew = e[rq];
                oacc[rq][0].x = fmaf(ew, v0.x, oacc[rq][0].x); oacc[rq][0].y = fmaf(ew, v0.y, oacc[rq][0].y);
                oacc[rq][0].z = fmaf(ew, v0.z, oacc[rq][0].z); oacc[rq][0].w = fmaf(ew, v0.w, oacc[rq][0].w);
                oacc[rq][1].x = fmaf(ew, v1.x, oacc[rq][1].x); oacc[rq][1].y = fmaf(ew, v1.y, oacc[rq][1].y);
                oacc[rq][1].z = fmaf(ew, v1.z, oacc[rq][1].z); oacc[rq][1].w = fmaf(ew, v1.w, oacc[rq][1].w);
                oacc[rq][2].x = fmaf(ew, v2.x, oacc[rq][2].x); oacc[rq][2].y = fmaf(ew, v2.y, oacc[rq][2].y);
                oacc[rq][2].z = fmaf(ew, v2.z, oacc[rq][2].z); oacc[rq][2].w = fmaf(ew, v2.w, oacc[rq][2].w);
                oacc[rq][3].x = fmaf(ew, v3.x, oacc[rq][3].x); oacc[rq][3].y = fmaf(ew, v3.y, oacc[rq][3].y);
                oacc[rq][3].z = fmaf(ew, v3.z, oacc[rq][3].z); oacc[rq][3].w = fmaf(ew, v3.w, oacc[rq][3].w);
            }
            // rotate double-buffer
#pragma unroll
            for (int i = 0; i < 4; i++) { kc[i] = kn[i]; vc[i] = vn[i]; }
        }
    }
    __syncthreads();
#pragma unroll
    for (int rq = 0; rq < 4; rq++) {
        float* rp = smem + (((w * 4 + rq) * 64 + lane)) * 17;   // stride 17: 2 lanes/bank, free
#pragma unroll
        for (int j = 0; j < 4; j++) {
            rp[4 * j + 0] = oacc[rq][j].x; rp[4 * j + 1] = oacc[rq][j].y;
            rp[4 * j + 2] = oacc[rq][j].z; rp[4 * j + 3] = oacc[rq][j].w;
        }
        rp[16] = lsum[rq];
    }
    __syncthreads();
    if (w < 4) {
        int rq = w;
        float acc[DD]; float lt = 0.f;
#pragma unroll
        for (int d = 0; d < DD; d++) acc[d] = 0.f;
#pragma unroll
        for (int p = 0; p < 8; p++) {
            const float* pp = smem + (((p * 4 + rq) * 64 + lane)) * 17;
#pragma unroll
            for (int d = 0; d < DD; d++) acc[d] += pp[d];
            lt += pp[16];
        }
        float inv = 1.0f / lt;
        int q = qbase + rq * 64 + lane;
        float* op = O + (long long)(b * NN + q) * EE + h * DD;
        float4 r0 = {acc[0]*inv, acc[1]*inv, acc[2]*inv, acc[3]*inv};
        float4 r1 = {acc[4]*inv, acc[5]*inv, acc[6]*inv, acc[7]*inv};
        float4 r2 = {acc[8]*inv, acc[9]*inv, acc[10]*inv, acc[11]*inv};
        float4 r3 = {acc[12]*inv, acc[13]*inv, acc[14]*inv, acc[15]*inv};
        ((float4*)op)[0] = r0; ((float4*)op)[1] = r1; ((float4*)op)[2] = r2; ((float4*)op)[3] = r3;
    }
}

// ---------------- out-projection + ReLU (standalone, used for layer 1) ----------------
__global__ __launch_bounds__(256) void k_out(const float* __restrict__ X, const float* __restrict__ WO,
                                             const float* __restrict__ bO, float* __restrict__ Y) {
    int lane = threadIdx.x & 63, quarter = threadIdx.x >> 6;
    long long row = (long long)blockIdx.x * 64 + lane;
    float xr[64];
    const float4* xp = (const float4*)(X + row * 64);
#pragma unroll
    for (int i = 0; i < 16; i++) {
        float4 t = xp[i];
        xr[4 * i] = t.x; xr[4 * i + 1] = t.y; xr[4 * i + 2] = t.z; xr[4 * i + 3] = t.w;
    }
    for (int jq = 0; jq < 4; jq++) {
        int j = quarter * 16 + jq * 4;
        float4 acc = *(const float4*)(bO + j);
#pragma unroll
        for (int f = 0; f < 64; f++) {
            float4 w4 = *(const float4*)(WO + f * 64 + j);
            acc.x = fmaf(xr[f], w4.x, acc.x);
            acc.y = fmaf(xr[f], w4.y, acc.y);
            acc.z = fmaf(xr[f], w4.z, acc.z);
            acc.w = fmaf(xr[f], w4.w, acc.w);
        }
        acc.x = fmaxf(acc.x, 0.f); acc.y = fmaxf(acc.y, 0.f);
        acc.z = fmaxf(acc.z, 0.f); acc.w = fmaxf(acc.w, 0.f);
        *(float4*)(Y + row * 64 + j) = acc;
    }
}

// ---------------- fused: out-proj(L0)+ReLU -> QKV proj (L1), x1 never touches HBM ----------------
__global__ __launch_bounds__(256) void k_outqkv(const float* __restrict__ O, const float* __restrict__ WO,
                                                const float* __restrict__ bO,
                                                const float* __restrict__ CW, const float* __restrict__ bQ,
                                                float* __restrict__ Q, float* __restrict__ K, float* __restrict__ V) {
    __shared__ float xs[64 * 68];
    int lane = threadIdx.x & 63, quarter = threadIdx.x >> 6;
    long long row = (long long)blockIdx.x * 64 + lane;
    int b = (int)(row >> 11), n = (int)(row & (NN - 1));
    {
        float xr[64];
        const float4* xp = (const float4*)(O + row * 64);
#pragma unroll
        for (int i = 0; i < 16; i++) {
            float4 t = xp[i];
            xr[4 * i] = t.x; xr[4 * i + 1] = t.y; xr[4 * i + 2] = t.z; xr[4 * i + 3] = t.w;
        }
        for (int jq = 0; jq < 4; jq++) {
            int j = quarter * 16 + jq * 4;
            float4 acc = *(const float4*)(bO + j);
#pragma unroll
            for (int f = 0; f < 64; f++) {
                float4 w4 = *(const float4*)(WO + f * 64 + j);
                acc.x = fmaf(xr[f], w4.x, acc.x);
                acc.y = fmaf(xr[f], w4.y, acc.y);
                acc.z = fmaf(xr[f], w4.z, acc.z);
                acc.w = fmaf(xr[f], w4.w, acc.w);
            }
            acc.x = fmaxf(acc.x, 0.f); acc.y = fmaxf(acc.y, 0.f);
            acc.z = fmaxf(acc.z, 0.f); acc.w = fmaxf(acc.w, 0.f);
            *(float4*)(xs + lane * 68 + j) = acc;
        }
    }
    __syncthreads();
    {
        float xr[64];
        const float4* xp = (const float4*)(xs + lane * 68);
#pragma unroll
        for (int i = 0; i < 16; i++) {
            float4 t = xp[i];
            xr[4 * i] = t.x; xr[4 * i + 1] = t.y; xr[4 * i + 2] = t.z; xr[4 * i + 3] = t.w;
        }
        for (int jq = 0; jq < 12; jq++) {
            int j = quarter * 48 + jq * 4;
            float4 acc = *(const float4*)(bQ + j);
#pragma unroll
            for (int f = 0; f < 64; f++) {
                float4 w4 = *(const float4*)(CW + f * 192 + j);
                acc.x = fmaf(xr[f], w4.x, acc.x);
                acc.y = fmaf(xr[f], w4.y, acc.y);
                acc.z = fmaf(xr[f], w4.z, acc.z);
                acc.w = fmaf(xr[f], w4.w, acc.w);
            }
            int which = j >> 6, c = j & 63, h = c >> 4, d = c & 15;
            float* dst = (which == 0) ? Q : ((which == 1) ? K : V);
            *(float4*)(dst + (((long long)(b * HH + h) * NN + n) * DD + d)) = acc;
        }
    }
}

// ---------------- fused 3-layer MLP head v2: 2-pass stage2, padded LDS ----------------
__global__ __launch_bounds__(128) void k_head(const float* __restrict__ X,
                                              const float* __restrict__ w1, const float* __restrict__ b1,
                                              const float* __restrict__ w2, const float* __restrict__ b2,
                                              const float* __restrict__ w3, const float* __restrict__ b3,
                                              float* __restrict__ out) {
    __shared__ float Xs[16 * 64];
    __shared__ float H1[16 * 132];
    __shared__ float H2[16 * 132];
    int tid = threadIdx.x;
    long long row0 = (long long)blockIdx.x * 16;
    {
        const float4* src = (const float4*)(X + row0 * 64);
        float4* dst = (float4*)Xs;
        dst[tid] = src[tid];
        dst[tid + 128] = src[tid + 128];
    }
    __syncthreads();
    {
        float wr[64];
#pragma unroll
        for (int f = 0; f < 64; f++) wr[f] = w1[f * 128 + tid];
        float bb = b1[tid];
        for (int r = 0; r < 16; r++) {
            const float4* x4 = (const float4*)(Xs + r * 64);
            float a0 = bb, a1 = 0.f, a2 = 0.f, a3 = 0.f;
#pragma unroll
            for (int fq = 0; fq < 16; fq++) {
                float4 xv = x4[fq];
                a0 = fmaf(xv.x, wr[4 * fq], a0);
                a1 = fmaf(xv.y, wr[4 * fq + 1], a1);
                a2 = fmaf(xv.z, wr[4 * fq + 2], a2);
                a3 = fmaf(xv.w, wr[4 * fq + 3], a3);
            }
            H1[r * 132 + tid] = fmaxf((a0 + a1) + (a2 + a3), 0.f);
        }
    }
    __syncthreads();
    {
        float acc2[16];
        float bb2 = b2[tid];
#pragma unroll
        for (int r = 0; r < 16; r++) acc2[r] = bb2;
#pragma unroll
        for (int p = 0; p < 2; p++) {
            float wr2[64];
#pragma unroll
            for (int i = 0; i < 64; i++) wr2[i] = w2[(p * 64 + i) * 128 + tid];
            for (int r = 0; r < 16; r++) {
                const float4* h4 = (const float4*)(H1 + r * 132 + p * 64);
                float a0 = 0.f, a1 = 0.f, a2 = 0.f, a3 = 0.f;
#pragma unroll
                for (int fq = 0; fq < 16; fq++) {
                    float4 xv = h4[fq];
                    a0 = fmaf(xv.x, wr2[4 * fq], a0);
                    a1 = fmaf(xv.y, wr2[4 * fq + 1], a1);
                    a2 = fmaf(xv.z, wr2[4 * fq + 2], a2);
                    a3 = fmaf(xv.w, wr2[4 * fq + 3], a3);
                }
                acc2[r] += (a0 + a1) + (a2 + a3);
            }
        }
#pragma unroll
        for (int r = 0; r < 16; r++) H2[r * 132 + tid] = fmaxf(acc2[r], 0.f);
    }
    __syncthreads();
    if (tid < 64) {
        int r = tid >> 2, a = tid & 3;
        float acc = b3[a];
        for (int f = 0; f < 128; f++) acc = fmaf(H2[r * 132 + f], w3[f * 4 + a], acc);
        out[(row0 + r) * 4 + a] = acc;
    }
}

extern "C" void kernel_launch(void* const* d_in, const int* in_sizes, int n_in,
                              void* d_out, int out_size, void* d_ws, size_t ws_size,
                              hipStream_t stream) {
    const float* nf = (const float*)d_in[0];
    const float* adj = (const float*)d_in[1];
    const float* l0[9]; for (int i = 0; i < 9; i++) l0[i] = (const float*)d_in[2 + i];
    const float* l1[9]; for (int i = 0; i < 9; i++) l1[i] = (const float*)d_in[11 + i];
    const float* hw1 = (const float*)d_in[20]; const float* hb1 = (const float*)d_in[21];
    const float* hw2 = (const float*)d_in[22]; const float* hb2 = (const float*)d_in[23];
    const float* hw3 = (const float*)d_in[24]; const float* hb3 = (const float*)d_in[25];
    float* out = (float*)d_out;

    char* ws = (char*)d_ws;
    size_t off = 0;
    auto alloc = [&](size_t bytes) -> void* {
        void* p = ws + off;
        off = (off + bytes + 255) & ~(size_t)255;
        return p;
    };
    unsigned long long* mbT = (unsigned long long*)alloc((size_t)BB * NN * NN / 8);
    float* Q = (float*)alloc((size_t)BB * HH * NN * DD * 4);
    float* K = (float*)alloc((size_t)BB * HH * NN * DD * 4);
    float* V = (float*)alloc((size_t)BB * HH * NN * DD * 4);
    float* O = (float*)alloc((size_t)BB * NN * EE * 4);
    float* x2 = (float*)alloc((size_t)BB * NN * EE * 4);
    float* CW0 = (float*)alloc(16 * 192 * 4);
    float* CW1 = (float*)alloc(64 * 192 * 4);
    float* WO0 = (float*)alloc(64 * 64 * 4);
    float* WO1 = (float*)alloc(64 * 64 * 4);
    float* bO0 = (float*)alloc(64 * 4);
    float* bO1 = (float*)alloc(64 * 4);
    float* bQ0 = (float*)alloc(192 * 4);
    float* bQ1 = (float*)alloc(192 * 4);

    k_mask<<<4096, 256, 0, stream>>>(adj, mbT);
    k_wcomb<<<dim3(65, 2), 256, 0, stream>>>(
        l0[0], l0[1], l0[2], l0[3], l0[4], l0[5], l0[6], l0[7], l0[8],
        l1[0], l1[1], l1[2], l1[3], l1[4], l1[5], l1[6], l1[7], l1[8],
        CW0, WO0, bO0, bQ0, CW1, WO1, bO1, bQ1);

    // layer 0 (feature scale folded into CW0)
    k_qkv<16><<<BB * NN / 64, 256, 0, stream>>>(nf, CW0, bQ0, Q, K, V);
    k_attn<<<dim3(NN / 256, HH, BB), 512, 0, stream>>>(Q, K, V, mbT, O);
    // fused: out-proj L0 + QKV proj L1
    k_outqkv<<<BB * NN / 64, 256, 0, stream>>>(O, WO0, bO0, CW1, bQ1, Q, K, V);
    k_attn<<<dim3(NN / 256, HH, BB), 512, 0, stream>>>(Q, K, V, mbT, O);
    k_out<<<BB * NN / 64, 256, 0, stream>>>(O, WO1, bO1, x2);
    // head
    k_head<<<BB * NN / 16, 128, 0, stream>>>(x2, hw1, hb1, hw2, hb2, hw3, hb3, out);
}

// Round 6
// 626.510 us; speedup vs baseline: 1.0346x; 1.0346x over previous
//
#include <hip/hip_runtime.h>

#define BB 8
#define NN 2048
#define FIN0 16
#define EE 64
#define HH 4
#define DD 16
#define HIDN 128
#define AA 4

// ---------------- adjacency -> blocked bitmask, TRANSPOSED: mbT[b][kblk][q] ----------------
__global__ __launch_bounds__(256) void k_mask(const float* __restrict__ adj, unsigned long long* __restrict__ mbT) {
    const int ITER = 32;
    for (int it = 0; it < ITER; it++) {
        long long idx = ((long long)blockIdx.x * ITER + it) * 256 + threadIdx.x;  // b*N*N + r*N + k
        int k = (int)(idx & (NN - 1));
        int r = (int)((idx >> 11) & (NN - 1));
        int b = (int)(idx >> 22);
        float a = adj[idx];
        bool blocked = (a == 0.0f) && (k != r);
        unsigned long long m = __ballot(blocked);
        if ((threadIdx.x & 63) == 0) mbT[((long long)b * 32 + (k >> 6)) * NN + r] = m;
    }
}

// ---------------- fold weights: CW = {wq,wk,wv}@in_w (Q cols pre-scaled), WO = mha_ow@op_w ----------------
#define QSCALE 0.36067376022224085f   // 0.25 * log2(e)
__device__ __forceinline__ float sfeat(int f) {
    return (f == 4 || f == 14 || f == 15) ? 1.0f : ((f == 5) ? (1.0f / 300.0f) : 0.02f);
}
__global__ __launch_bounds__(256) void k_wcomb(
        const float* __restrict__ wq0, const float* __restrict__ wk0, const float* __restrict__ wv0,
        const float* __restrict__ inw0, const float* __restrict__ inb0,
        const float* __restrict__ mow0, const float* __restrict__ mob0,
        const float* __restrict__ opw0, const float* __restrict__ opb0,
        const float* __restrict__ wq1, const float* __restrict__ wk1, const float* __restrict__ wv1,
        const float* __restrict__ inw1, const float* __restrict__ inb1,
        const float* __restrict__ mow1, const float* __restrict__ mob1,
        const float* __restrict__ opw1, const float* __restrict__ opb1,
        float* __restrict__ CW0, float* __restrict__ WO0, float* __restrict__ bO0, float* __restrict__ bQ0,
        float* __restrict__ CW1, float* __restrict__ WO1, float* __restrict__ bO1, float* __restrict__ bQ1) {
    int ly = blockIdx.y;
    int fin = ly ? EE : FIN0;
    const float* wq = ly ? wq1 : wq0; const float* wk = ly ? wk1 : wk0; const float* wv = ly ? wv1 : wv0;
    const float* inw = ly ? inw1 : inw0; const float* inb = ly ? inb1 : inb0;
    const float* mow = ly ? mow1 : mow0; const float* mob = ly ? mob1 : mob0;
    const float* opw = ly ? opw1 : opw0; const float* opb = ly ? opb1 : opb0;
    float* CW = ly ? CW1 : CW0; float* WO = ly ? WO1 : WO0;
    float* bO = ly ? bO1 : bO0; float* bQ = ly ? bQ1 : bQ0;

    int t = blockIdx.x * 256 + threadIdx.x;
    int t1 = fin * 192;
    int t2 = t1 + 4096;
    int t3 = t2 + 64;
    int t4 = t3 + 192;
    if (t < t1) {
        int f = t / 192, j = t % 192;
        const float* w = (j < 64) ? wq : ((j < 128) ? wk : wv);
        float acc = 0.f;
        for (int kk = 0; kk < 64; kk++) acc += w[f * 64 + kk] * inw[kk * 192 + j];
        if (j < 64) acc *= QSCALE;
        if (ly == 0) acc *= sfeat(f);
        CW[t] = acc;
    } else if (t < t2) {
        int u = t - t1; int i = u >> 6, j = u & 63;
        float acc = 0.f;
        for (int kk = 0; kk < 64; kk++) acc += mow[i * 64 + kk] * opw[kk * 64 + j];
        WO[u] = acc;
    } else if (t < t3) {
        int j = t - t2;
        float acc = opb[j];
        for (int kk = 0; kk < 64; kk++) acc += mob[kk] * opw[kk * 64 + j];
        bO[j] = acc;
    } else if (t < t4) {
        int j = t - t3;
        bQ[j] = inb[j] * ((j < 64) ? QSCALE : 1.0f);
    }
}

// ---------------- fused QKV projection (layer 0): X[B*N][fin] @ CW + bQ -> Q,K,V [B][H][N][D] ----------------
template <int FINP>
__global__ __launch_bounds__(256) void k_qkv(const float* __restrict__ X, const float* __restrict__ CW,
                                             const float* __restrict__ bQ,
                                             float* __restrict__ Q, float* __restrict__ K, float* __restrict__ V) {
    int lane = threadIdx.x & 63;
    int quarter = threadIdx.x >> 6;
    int row = blockIdx.x * 64 + lane;
    int b = row >> 11, n = row & (NN - 1);
    float xr[FINP];
    const float4* xp = (const float4*)(X + (long long)row * FINP);
#pragma unroll
    for (int i = 0; i < FINP / 4; i++) {
        float4 v = xp[i];
        xr[4 * i] = v.x; xr[4 * i + 1] = v.y; xr[4 * i + 2] = v.z; xr[4 * i + 3] = v.w;
    }
    for (int jq = 0; jq < 12; jq++) {
        int j = quarter * 48 + jq * 4;
        float4 acc = *(const float4*)(bQ + j);
#pragma unroll
        for (int f = 0; f < FINP; f++) {
            float4 w = *(const float4*)(CW + f * 192 + j);
            acc.x = fmaf(xr[f], w.x, acc.x);
            acc.y = fmaf(xr[f], w.y, acc.y);
            acc.z = fmaf(xr[f], w.z, acc.z);
            acc.w = fmaf(xr[f], w.w, acc.w);
        }
        int which = j >> 6, c = j & 63, h = c >> 4, d = c & 15;
        float* dst = (which == 0) ? Q : ((which == 1) ? K : V);
        *(float4*)(dst + (((long long)(b * HH + h) * NN + n) * DD + d)) = acc;
    }
}

// ---------------- attention v6: HYBRID — K via wave-private LDS, V streamed from global ----------------
// K: staged per 64-row chunk into wave-private LDS with register prefetch (4 ds_read_b128/iter,
// ~384 cyc/CU-round < VALU ~600). V: wave-uniform broadcast global loads, explicit 2-row-deep
// register double-buffer (load row idx+2 while computing idx -> ~2-iter distance >> L2 latency).
// Total VGPR ~200 fits the 256 cap of launch_bounds(512,2); LDS caps us at 1 block/CU anyway.
__global__ __launch_bounds__(512, 2) void k_attn(const float* __restrict__ Q, const float* __restrict__ K,
                                                 const float* __restrict__ V,
                                                 const unsigned long long* __restrict__ mbT,
                                                 float* __restrict__ O) {
    __shared__ float smem[8 * 4 * 64 * 17];            // K staging (first 8*1024 floats) + reduction overlay
    int lane = threadIdx.x & 63;
    int w = threadIdx.x >> 6;                          // k-eighth owner (256 rows)
    int qb = blockIdx.x, h = blockIdx.y, b = blockIdx.z;
    int qbase = qb * 256;

    const float* Qbh = Q + (long long)(b * HH + h) * NN * DD;
    const float* Kb  = K + (long long)(b * HH + h) * NN * DD;
    const float* Vb  = V + (long long)(b * HH + h) * NN * DD;
    const unsigned long long* mrow = mbT + (long long)b * 32 * NN;

    float4 qf[4][4];
#pragma unroll
    for (int rq = 0; rq < 4; rq++) {
        const float4* qp = (const float4*)(Qbh + (long long)(qbase + rq * 64 + lane) * DD);
#pragma unroll
        for (int j = 0; j < 4; j++) qf[rq][j] = qp[j];
    }
    float4 oacc[4][4];
#pragma unroll
    for (int rq = 0; rq < 4; rq++)
#pragma unroll
        for (int j = 0; j < 4; j++) oacc[rq][j] = make_float4(0.f, 0.f, 0.f, 0.f);
    float lsum[4] = {0.f, 0.f, 0.f, 0.f};

    float* sK = smem + w * 1024;                       // wave-private K chunk (64 rows x 16)
    const float4* kp4 = (const float4*)(Kb + (long long)(w * 256) * DD);
    const float4* vp4 = (const float4*)(Vb + (long long)(w * 256) * DD);

    // prologue: K chunk 0 into regs, V rows 0/1 into the double-buffer, masks chunk 0
    float4 kpre[4];
#pragma unroll
    for (int i = 0; i < 4; i++) kpre[i] = kp4[lane + 64 * i];
    float4 vb0[4], vb1[4];
#pragma unroll
    for (int i = 0; i < 4; i++) { vb0[i] = vp4[i]; vb1[i] = vp4[4 + i]; }
    unsigned long long mwpre[4];
#pragma unroll
    for (int rq = 0; rq < 4; rq++) mwpre[rq] = mrow[(long long)(w * 4) * NN + qbase + rq * 64 + lane];

    for (int c = 0; c < 4; c++) {
        // stage prefetched K chunk into wave-private LDS
#pragma unroll
        for (int i = 0; i < 4; i++) ((float4*)sK)[lane + 64 * i] = kpre[i];
        unsigned long long mw[4];
#pragma unroll
        for (int rq = 0; rq < 4; rq++) mw[rq] = mwpre[rq];
        // prefetch next chunk's K + masks (mask last-iter overread lands in next ws buffer)
        if (c < 3) {
#pragma unroll
            for (int i = 0; i < 4; i++) kpre[i] = kp4[(c + 1) * 256 + lane + 64 * i];
        }
        {
            int kblkn = w * 4 + c + 1;
#pragma unroll
            for (int rq = 0; rq < 4; rq++) mwpre[rq] = mrow[(long long)kblkn * NN + qbase + rq * 64 + lane];
        }
        asm volatile("s_waitcnt lgkmcnt(0)" ::: "memory");   // wave-private LDS writes visible
#pragma unroll 2
        for (int kk2 = 0; kk2 < 32; kk2++) {
            int idx = c * 64 + kk2 * 2;
#pragma unroll 2
            for (int par = 0; par < 2; par++) {
                int kk = kk2 * 2 + par;
                // grab this row's V from the double-buffer, immediately refill for row idx+2(+par)
                float4 v0, v1, v2, v3;
                if (par == 0) {
                    v0 = vb0[0]; v1 = vb0[1]; v2 = vb0[2]; v3 = vb0[3];
#pragma unroll
                    for (int i = 0; i < 4; i++) vb0[i] = vp4[(idx + 2) * 4 + i];   // overreads <=2 rows past range: lands in next ws buffer
                } else {
                    v0 = vb1[0]; v1 = vb1[1]; v2 = vb1[2]; v3 = vb1[3];
#pragma unroll
                    for (int i = 0; i < 4; i++) vb1[i] = vp4[(idx + 3) * 4 + i];
                }
                const float4* kr = (const float4*)(sK + kk * 16);
                float4 k0 = kr[0], k1 = kr[1], k2 = kr[2], k3 = kr[3];
                float e[4];
#pragma unroll
                for (int rq = 0; rq < 4; rq++) {
                    float4 a0 = qf[rq][0], a1 = qf[rq][1], a2 = qf[rq][2], a3 = qf[rq][3];
                    float sA = a0.x * k0.x;
                    sA = fmaf(a0.y, k0.y, sA); sA = fmaf(a0.z, k0.z, sA); sA = fmaf(a0.w, k0.w, sA);
                    sA = fmaf(a1.x, k1.x, sA); sA = fmaf(a1.y, k1.y, sA); sA = fmaf(a1.z, k1.z, sA); sA = fmaf(a1.w, k1.w, sA);
                    float sB = a2.x * k2.x;
                    sB = fmaf(a2.y, k2.y, sB); sB = fmaf(a2.z, k2.z, sB); sB = fmaf(a2.w, k2.w, sB);
                    sB = fmaf(a3.x, k3.x, sB); sB = fmaf(a3.y, k3.y, sB); sB = fmaf(a3.z, k3.z, sB); sB = fmaf(a3.w, k3.w, sB);
                    float ee = __builtin_amdgcn_exp2f(sA + sB);     // softmax scale folded into Q
                    e[rq] = ((mw[rq] >> kk) & 1ULL) ? 0.f : ee;
                    lsum[rq] += e[rq];
                }
#pragma unroll
                for (int rq = 0; rq < 4; rq++) {
                    float ew = e[rq];
                    oacc[rq][0].x = fmaf(ew, v0.x, oacc[rq][0].x); oacc[rq][0].y = fmaf(ew, v0.y, oacc[rq][0].y);
                    oacc[rq][0].z = fmaf(ew, v0.z, oacc[rq][0].z); oacc[rq][0].w = fmaf(ew, v0.w, oacc[rq][0].w);
                    oacc[rq][1].x = fmaf(ew, v1.x, oacc[rq][1].x); oacc[rq][1].y = fmaf(ew, v1.y, oacc[rq][1].y);
                    oacc[rq][1].z = fmaf(ew, v1.z, oacc[rq][1].z); oacc[rq][1].w = fmaf(ew, v1.w, oacc[rq][1].w);
                    oacc[rq][2].x = fmaf(ew, v2.x, oacc[rq][2].x); oacc[rq][2].y = fmaf(ew, v2.y, oacc[rq][2].y);
                    oacc[rq][2].z = fmaf(ew, v2.z, oacc[rq][2].z); oacc[rq][2].w = fmaf(ew, v2.w, oacc[rq][2].w);
                    oacc[rq][3].x = fmaf(ew, v3.x, oacc[rq][3].x); oacc[rq][3].y = fmaf(ew, v3.y, oacc[rq][3].y);
                    oacc[rq][3].z = fmaf(ew, v3.z, oacc[rq][3].z); oacc[rq][3].w = fmaf(ew, v3.w, oacc[rq][3].w);
                }
            }
        }
    }
    __syncthreads();                                   // all K-staging reads done before overlay
#pragma unroll
    for (int rq = 0; rq < 4; rq++) {
        float* rp = smem + (((w * 4 + rq) * 64 + lane)) * 17;   // stride 17: 2 lanes/bank, free
#pragma unroll
        for (int j = 0; j < 4; j++) {
            rp[4 * j + 0] = oacc[rq][j].x; rp[4 * j + 1] = oacc[rq][j].y;
            rp[4 * j + 2] = oacc[rq][j].z; rp[4 * j + 3] = oacc[rq][j].w;
        }
        rp[16] = lsum[rq];
    }
    __syncthreads();
    if (w < 4) {
        int rq = w;
        float acc[DD]; float lt = 0.f;
#pragma unroll
        for (int d = 0; d < DD; d++) acc[d] = 0.f;
#pragma unroll
        for (int p = 0; p < 8; p++) {
            const float* pp = smem + (((p * 4 + rq) * 64 + lane)) * 17;
#pragma unroll
            for (int d = 0; d < DD; d++) acc[d] += pp[d];
            lt += pp[16];
        }
        float inv = 1.0f / lt;
        int q = qbase + rq * 64 + lane;
        float* op = O + (long long)(b * NN + q) * EE + h * DD;
        float4 r0 = {acc[0]*inv, acc[1]*inv, acc[2]*inv, acc[3]*inv};
        float4 r1 = {acc[4]*inv, acc[5]*inv, acc[6]*inv, acc[7]*inv};
        float4 r2 = {acc[8]*inv, acc[9]*inv, acc[10]*inv, acc[11]*inv};
        float4 r3 = {acc[12]*inv, acc[13]*inv, acc[14]*inv, acc[15]*inv};
        ((float4*)op)[0] = r0; ((float4*)op)[1] = r1; ((float4*)op)[2] = r2; ((float4*)op)[3] = r3;
    }
}

// ---------------- out-projection + ReLU (standalone, used for layer 1) ----------------
__global__ __launch_bounds__(256) void k_out(const float* __restrict__ X, const float* __restrict__ WO,
                                             const float* __restrict__ bO, float* __restrict__ Y) {
    int lane = threadIdx.x & 63, quarter = threadIdx.x >> 6;
    long long row = (long long)blockIdx.x * 64 + lane;
    float xr[64];
    const float4* xp = (const float4*)(X + row * 64);
#pragma unroll
    for (int i = 0; i < 16; i++) {
        float4 t = xp[i];
        xr[4 * i] = t.x; xr[4 * i + 1] = t.y; xr[4 * i + 2] = t.z; xr[4 * i + 3] = t.w;
    }
    for (int jq = 0; jq < 4; jq++) {
        int j = quarter * 16 + jq * 4;
        float4 acc = *(const float4*)(bO + j);
#pragma unroll
        for (int f = 0; f < 64; f++) {
            float4 w4 = *(const float4*)(WO + f * 64 + j);
            acc.x = fmaf(xr[f], w4.x, acc.x);
            acc.y = fmaf(xr[f], w4.y, acc.y);
            acc.z = fmaf(xr[f], w4.z, acc.z);
            acc.w = fmaf(xr[f], w4.w, acc.w);
        }
        acc.x = fmaxf(acc.x, 0.f); acc.y = fmaxf(acc.y, 0.f);
        acc.z = fmaxf(acc.z, 0.f); acc.w = fmaxf(acc.w, 0.f);
        *(float4*)(Y + row * 64 + j) = acc;
    }
}

// ---------------- fused: out-proj(L0)+ReLU -> QKV proj (L1), x1 never touches HBM ----------------
__global__ __launch_bounds__(256) void k_outqkv(const float* __restrict__ O, const float* __restrict__ WO,
                                                const float* __restrict__ bO,
                                                const float* __restrict__ CW, const float* __restrict__ bQ,
                                                float* __restrict__ Q, float* __restrict__ K, float* __restrict__ V) {
    __shared__ float xs[64 * 68];
    int lane = threadIdx.x & 63, quarter = threadIdx.x >> 6;
    long long row = (long long)blockIdx.x * 64 + lane;
    int b = (int)(row >> 11), n = (int)(row & (NN - 1));
    {
        float xr[64];
        const float4* xp = (const float4*)(O + row * 64);
#pragma unroll
        for (int i = 0; i < 16; i++) {
            float4 t = xp[i];
            xr[4 * i] = t.x; xr[4 * i + 1] = t.y; xr[4 * i + 2] = t.z; xr[4 * i + 3] = t.w;
        }
        for (int jq = 0; jq < 4; jq++) {
            int j = quarter * 16 + jq * 4;
            float4 acc = *(const float4*)(bO + j);
#pragma unroll
            for (int f = 0; f < 64; f++) {
                float4 w4 = *(const float4*)(WO + f * 64 + j);
                acc.x = fmaf(xr[f], w4.x, acc.x);
                acc.y = fmaf(xr[f], w4.y, acc.y);
                acc.z = fmaf(xr[f], w4.z, acc.z);
                acc.w = fmaf(xr[f], w4.w, acc.w);
            }
            acc.x = fmaxf(acc.x, 0.f); acc.y = fmaxf(acc.y, 0.f);
            acc.z = fmaxf(acc.z, 0.f); acc.w = fmaxf(acc.w, 0.f);
            *(float4*)(xs + lane * 68 + j) = acc;
        }
    }
    __syncthreads();
    {
        float xr[64];
        const float4* xp = (const float4*)(xs + lane * 68);
#pragma unroll
        for (int i = 0; i < 16; i++) {
            float4 t = xp[i];
            xr[4 * i] = t.x; xr[4 * i + 1] = t.y; xr[4 * i + 2] = t.z; xr[4 * i + 3] = t.w;
        }
        for (int jq = 0; jq < 12; jq++) {
            int j = quarter * 48 + jq * 4;
            float4 acc = *(const float4*)(bQ + j);
#pragma unroll
            for (int f = 0; f < 64; f++) {
                float4 w4 = *(const float4*)(CW + f * 192 + j);
                acc.x = fmaf(xr[f], w4.x, acc.x);
                acc.y = fmaf(xr[f], w4.y, acc.y);
                acc.z = fmaf(xr[f], w4.z, acc.z);
                acc.w = fmaf(xr[f], w4.w, acc.w);
            }
            int which = j >> 6, c = j & 63, h = c >> 4, d = c & 15;
            float* dst = (which == 0) ? Q : ((which == 1) ? K : V);
            *(float4*)(dst + (((long long)(b * HH + h) * NN + n) * DD + d)) = acc;
        }
    }
}

// ---------------- fused 3-layer MLP head v2: 2-pass stage2, padded LDS ----------------
__global__ __launch_bounds__(128) void k_head(const float* __restrict__ X,
                                              const float* __restrict__ w1, const float* __restrict__ b1,
                                              const float* __restrict__ w2, const float* __restrict__ b2,
                                              const float* __restrict__ w3, const float* __restrict__ b3,
                                              float* __restrict__ out) {
    __shared__ float Xs[16 * 64];
    __shared__ float H1[16 * 132];
    __shared__ float H2[16 * 132];
    int tid = threadIdx.x;
    long long row0 = (long long)blockIdx.x * 16;
    {
        const float4* src = (const float4*)(X + row0 * 64);
        float4* dst = (float4*)Xs;
        dst[tid] = src[tid];
        dst[tid + 128] = src[tid + 128];
    }
    __syncthreads();
    {
        float wr[64];
#pragma unroll
        for (int f = 0; f < 64; f++) wr[f] = w1[f * 128 + tid];
        float bb = b1[tid];
        for (int r = 0; r < 16; r++) {
            const float4* x4 = (const float4*)(Xs + r * 64);
            float a0 = bb, a1 = 0.f, a2 = 0.f, a3 = 0.f;
#pragma unroll
            for (int fq = 0; fq < 16; fq++) {
                float4 xv = x4[fq];
                a0 = fmaf(xv.x, wr[4 * fq], a0);
                a1 = fmaf(xv.y, wr[4 * fq + 1], a1);
                a2 = fmaf(xv.z, wr[4 * fq + 2], a2);
                a3 = fmaf(xv.w, wr[4 * fq + 3], a3);
            }
            H1[r * 132 + tid] = fmaxf((a0 + a1) + (a2 + a3), 0.f);
        }
    }
    __syncthreads();
    {
        float acc2[16];
        float bb2 = b2[tid];
#pragma unroll
        for (int r = 0; r < 16; r++) acc2[r] = bb2;
#pragma unroll
        for (int p = 0; p < 2; p++) {
            float wr2[64];
#pragma unroll
            for (int i = 0; i < 64; i++) wr2[i] = w2[(p * 64 + i) * 128 + tid];
            for (int r = 0; r < 16; r++) {
                const float4* h4 = (const float4*)(H1 + r * 132 + p * 64);
                float a0 = 0.f, a1 = 0.f, a2 = 0.f, a3 = 0.f;
#pragma unroll
                for (int fq = 0; fq < 16; fq++) {
                    float4 xv = h4[fq];
                    a0 = fmaf(xv.x, wr2[4 * fq], a0);
                    a1 = fmaf(xv.y, wr2[4 * fq + 1], a1);
                    a2 = fmaf(xv.z, wr2[4 * fq + 2], a2);
                    a3 = fmaf(xv.w, wr2[4 * fq + 3], a3);
                }
                acc2[r] += (a0 + a1) + (a2 + a3);
            }
        }
#pragma unroll
        for (int r = 0; r < 16; r++) H2[r * 132 + tid] = fmaxf(acc2[r], 0.f);
    }
    __syncthreads();
    if (tid < 64) {
        int r = tid >> 2, a = tid & 3;
        float acc = b3[a];
        for (int f = 0; f < 128; f++) acc = fmaf(H2[r * 132 + f], w3[f * 4 + a], acc);
        out[(row0 + r) * 4 + a] = acc;
    }
}

extern "C" void kernel_launch(void* const* d_in, const int* in_sizes, int n_in,
                              void* d_out, int out_size, void* d_ws, size_t ws_size,
                              hipStream_t stream) {
    const float* nf = (const float*)d_in[0];
    const float* adj = (const float*)d_in[1];
    const float* l0[9]; for (int i = 0; i < 9; i++) l0[i] = (const float*)d_in[2 + i];
    const float* l1[9]; for (int i = 0; i < 9; i++) l1[i] = (const float*)d_in[11 + i];
    const float* hw1 = (const float*)d_in[20]; const float* hb1 = (const float*)d_in[21];
    const float* hw2 = (const float*)d_in[22]; const float* hb2 = (const float*)d_in[23];
    const float* hw3 = (const float*)d_in[24]; const float* hb3 = (const float*)d_in[25];
    float* out = (float*)d_out;

    char* ws = (char*)d_ws;
    size_t off = 0;
    auto alloc = [&](size_t bytes) -> void* {
        void* p = ws + off;
        off = (off + bytes + 255) & ~(size_t)255;
        return p;
    };
    unsigned long long* mbT = (unsigned long long*)alloc((size_t)BB * NN * NN / 8);
    float* Q = (float*)alloc((size_t)BB * HH * NN * DD * 4);
    float* K = (float*)alloc((size_t)BB * HH * NN * DD * 4);
    float* V = (float*)alloc((size_t)BB * HH * NN * DD * 4);
    float* O = (float*)alloc((size_t)BB * NN * EE * 4);
    float* x2 = (float*)alloc((size_t)BB * NN * EE * 4);
    float* CW0 = (float*)alloc(16 * 192 * 4);
    float* CW1 = (float*)alloc(64 * 192 * 4);
    float* WO0 = (float*)alloc(64 * 64 * 4);
    float* WO1 = (float*)alloc(64 * 64 * 4);
    float* bO0 = (float*)alloc(64 * 4);
    float* bO1 = (float*)alloc(64 * 4);
    float* bQ0 = (float*)alloc(192 * 4);
    float* bQ1 = (float*)alloc(192 * 4);

    k_mask<<<4096, 256, 0, stream>>>(adj, mbT);
    k_wcomb<<<dim3(65, 2), 256, 0, stream>>>(
        l0[0], l0[1], l0[2], l0[3], l0[4], l0[5], l0[6], l0[7], l0[8],
        l1[0], l1[1], l1[2], l1[3], l1[4], l1[5], l1[6], l1[7], l1[8],
        CW0, WO0, bO0, bQ0, CW1, WO1, bO1, bQ1);

    // layer 0 (feature scale folded into CW0)
    k_qkv<16><<<BB * NN / 64, 256, 0, stream>>>(nf, CW0, bQ0, Q, K, V);
    k_attn<<<dim3(NN / 256, HH, BB), 512, 0, stream>>>(Q, K, V, mbT, O);
    // fused: out-proj L0 + QKV proj L1
    k_outqkv<<<BB * NN / 64, 256, 0, stream>>>(O, WO0, bO0, CW1, bQ1, Q, K, V);
    k_attn<<<dim3(NN / 256, HH, BB), 512, 0, stream>>>(Q, K, V, mbT, O);
    k_out<<<BB * NN / 64, 256, 0, stream>>>(O, WO1, bO1, x2);
    // head
    k_head<<<BB * NN / 16, 128, 0, stream>>>(x2, hw1, hb1, hw2, hb2, hw3, hb3, out);
}

// Round 7
// 626.492 us; speedup vs baseline: 1.0346x; 1.0000x over previous
//
#include <hip/hip_runtime.h>

#define BB 8
#define NN 2048
#define FIN0 16
#define EE 64
#define HH 4
#define DD 16
#define HIDN 128
#define AA 4

// ---------------- adjacency -> blocked bitmask, TRANSPOSED: mbT[b][kblk][q] ----------------
__global__ __launch_bounds__(256) void k_mask(const float* __restrict__ adj, unsigned long long* __restrict__ mbT) {
    const int ITER = 32;
    for (int it = 0; it < ITER; it++) {
        long long idx = ((long long)blockIdx.x * ITER + it) * 256 + threadIdx.x;  // b*N*N + r*N + k
        int k = (int)(idx & (NN - 1));
        int r = (int)((idx >> 11) & (NN - 1));
        int b = (int)(idx >> 22);
        float a = adj[idx];
        bool blocked = (a == 0.0f) && (k != r);
        unsigned long long m = __ballot(blocked);
        if ((threadIdx.x & 63) == 0) mbT[((long long)b * 32 + (k >> 6)) * NN + r] = m;
    }
}

// ---------------- fold weights: CW = {wq,wk,wv}@in_w (Q cols pre-scaled), WO = mha_ow@op_w ----------------
#define QSCALE 0.36067376022224085f   // 0.25 * log2(e)
__device__ __forceinline__ float sfeat(int f) {
    return (f == 4 || f == 14 || f == 15) ? 1.0f : ((f == 5) ? (1.0f / 300.0f) : 0.02f);
}
__global__ __launch_bounds__(256) void k_wcomb(
        const float* __restrict__ wq0, const float* __restrict__ wk0, const float* __restrict__ wv0,
        const float* __restrict__ inw0, const float* __restrict__ inb0,
        const float* __restrict__ mow0, const float* __restrict__ mob0,
        const float* __restrict__ opw0, const float* __restrict__ opb0,
        const float* __restrict__ wq1, const float* __restrict__ wk1, const float* __restrict__ wv1,
        const float* __restrict__ inw1, const float* __restrict__ inb1,
        const float* __restrict__ mow1, const float* __restrict__ mob1,
        const float* __restrict__ opw1, const float* __restrict__ opb1,
        float* __restrict__ CW0, float* __restrict__ WO0, float* __restrict__ bO0, float* __restrict__ bQ0,
        float* __restrict__ CW1, float* __restrict__ WO1, float* __restrict__ bO1, float* __restrict__ bQ1) {
    int ly = blockIdx.y;
    int fin = ly ? EE : FIN0;
    const float* wq = ly ? wq1 : wq0; const float* wk = ly ? wk1 : wk0; const float* wv = ly ? wv1 : wv0;
    const float* inw = ly ? inw1 : inw0; const float* inb = ly ? inb1 : inb0;
    const float* mow = ly ? mow1 : mow0; const float* mob = ly ? mob1 : mob0;
    const float* opw = ly ? opw1 : opw0; const float* opb = ly ? opb1 : opb0;
    float* CW = ly ? CW1 : CW0; float* WO = ly ? WO1 : WO0;
    float* bO = ly ? bO1 : bO0; float* bQ = ly ? bQ1 : bQ0;

    int t = blockIdx.x * 256 + threadIdx.x;
    int t1 = fin * 192;
    int t2 = t1 + 4096;
    int t3 = t2 + 64;
    int t4 = t3 + 192;
    if (t < t1) {
        int f = t / 192, j = t % 192;
        const float* w = (j < 64) ? wq : ((j < 128) ? wk : wv);
        float acc = 0.f;
        for (int kk = 0; kk < 64; kk++) acc += w[f * 64 + kk] * inw[kk * 192 + j];
        if (j < 64) acc *= QSCALE;
        if (ly == 0) acc *= sfeat(f);
        CW[t] = acc;
    } else if (t < t2) {
        int u = t - t1; int i = u >> 6, j = u & 63;
        float acc = 0.f;
        for (int kk = 0; kk < 64; kk++) acc += mow[i * 64 + kk] * opw[kk * 64 + j];
        WO[u] = acc;
    } else if (t < t3) {
        int j = t - t2;
        float acc = opb[j];
        for (int kk = 0; kk < 64; kk++) acc += mob[kk] * opw[kk * 64 + j];
        bO[j] = acc;
    } else if (t < t4) {
        int j = t - t3;
        bQ[j] = inb[j] * ((j < 64) ? QSCALE : 1.0f);
    }
}

// ---------------- fused QKV projection (layer 0): X[B*N][fin] @ CW + bQ -> Q,K,V [B][H][N][D] ----------------
template <int FINP>
__global__ __launch_bounds__(256) void k_qkv(const float* __restrict__ X, const float* __restrict__ CW,
                                             const float* __restrict__ bQ,
                                             float* __restrict__ Q, float* __restrict__ K, float* __restrict__ V) {
    int lane = threadIdx.x & 63;
    int quarter = threadIdx.x >> 6;
    int row = blockIdx.x * 64 + lane;
    int b = row >> 11, n = row & (NN - 1);
    float xr[FINP];
    const float4* xp = (const float4*)(X + (long long)row * FINP);
#pragma unroll
    for (int i = 0; i < FINP / 4; i++) {
        float4 v = xp[i];
        xr[4 * i] = v.x; xr[4 * i + 1] = v.y; xr[4 * i + 2] = v.z; xr[4 * i + 3] = v.w;
    }
    for (int jq = 0; jq < 12; jq++) {
        int j = quarter * 48 + jq * 4;
        float4 acc = *(const float4*)(bQ + j);
#pragma unroll
        for (int f = 0; f < FINP; f++) {
            float4 w = *(const float4*)(CW + f * 192 + j);
            acc.x = fmaf(xr[f], w.x, acc.x);
            acc.y = fmaf(xr[f], w.y, acc.y);
            acc.z = fmaf(xr[f], w.z, acc.z);
            acc.w = fmaf(xr[f], w.w, acc.w);
        }
        int which = j >> 6, c = j & 63, h = c >> 4, d = c & 15;
        float* dst = (which == 0) ? Q : ((which == 1) ? K : V);
        *(float4*)(dst + (((long long)(b * HH + h) * NN + n) * DD + d)) = acc;
    }
}

// ---------------- attention v7: hybrid (K via LDS, V streamed) with PINNED 2 waves/EU ----------------
// v6's failure mode was the allocator pinning 128 VGPRs (4 waves/SIMD heuristic) and spilling
// the V double-buffer to scratch (WRITE_SIZE 4096->27727 KB). amdgpu_waves_per_eu(2,2) pins the
// occupancy target to what we actually run (1 block/CU x 8 waves = 2/EU), giving the allocator
// the full 256-VGPR budget so vb0/vb1 stay in registers.
// K: wave-private LDS chunk w/ register prefetch (4 ds_read_b128/iter -> ~384 LDS-cyc/CU-round).
// V: wave-uniform broadcast global loads, 2-row-deep register double-buffer (~2-iter distance
// >> ~200cyc L2 latency). VALU (~592 cyc/round) becomes the binding pipe.
__global__ __launch_bounds__(512) __attribute__((amdgpu_waves_per_eu(2, 2)))
void k_attn(const float* __restrict__ Q, const float* __restrict__ K,
            const float* __restrict__ V,
            const unsigned long long* __restrict__ mbT,
            float* __restrict__ O) {
    __shared__ float smem[8 * 4 * 64 * 17];            // K staging (first 8*1024 floats) + reduction overlay
    int lane = threadIdx.x & 63;
    int w = threadIdx.x >> 6;                          // k-eighth owner (256 rows)
    int qb = blockIdx.x, h = blockIdx.y, b = blockIdx.z;
    int qbase = qb * 256;

    const float* Qbh = Q + (long long)(b * HH + h) * NN * DD;
    const float* Kb  = K + (long long)(b * HH + h) * NN * DD;
    const float* Vb  = V + (long long)(b * HH + h) * NN * DD;
    const unsigned long long* mrow = mbT + (long long)b * 32 * NN;

    float4 qf[4][4];
#pragma unroll
    for (int rq = 0; rq < 4; rq++) {
        const float4* qp = (const float4*)(Qbh + (long long)(qbase + rq * 64 + lane) * DD);
#pragma unroll
        for (int j = 0; j < 4; j++) qf[rq][j] = qp[j];
    }
    float4 oacc[4][4];
#pragma unroll
    for (int rq = 0; rq < 4; rq++)
#pragma unroll
        for (int j = 0; j < 4; j++) oacc[rq][j] = make_float4(0.f, 0.f, 0.f, 0.f);
    float lsum[4] = {0.f, 0.f, 0.f, 0.f};

    float* sK = smem + w * 1024;                       // wave-private K chunk (64 rows x 16)
    const float4* kp4 = (const float4*)(Kb + (long long)(w * 256) * DD);
    const float4* vp4 = (const float4*)(Vb + (long long)(w * 256) * DD);

    // prologue: K chunk 0 into regs, V rows 0/1 into the double-buffer, masks chunk 0
    float4 kpre[4];
#pragma unroll
    for (int i = 0; i < 4; i++) kpre[i] = kp4[lane + 64 * i];
    float4 vb0[4], vb1[4];
#pragma unroll
    for (int i = 0; i < 4; i++) { vb0[i] = vp4[i]; vb1[i] = vp4[4 + i]; }
    unsigned long long mwpre[4];
#pragma unroll
    for (int rq = 0; rq < 4; rq++) mwpre[rq] = mrow[(long long)(w * 4) * NN + qbase + rq * 64 + lane];

    for (int c = 0; c < 4; c++) {
        // stage prefetched K chunk into wave-private LDS
#pragma unroll
        for (int i = 0; i < 4; i++) ((float4*)sK)[lane + 64 * i] = kpre[i];
        unsigned long long mw[4];
#pragma unroll
        for (int rq = 0; rq < 4; rq++) mw[rq] = mwpre[rq];
        // prefetch next chunk's K + masks (mask last-iter overread lands in next ws buffer)
        if (c < 3) {
#pragma unroll
            for (int i = 0; i < 4; i++) kpre[i] = kp4[(c + 1) * 256 + lane + 64 * i];
        }
        {
            int kblkn = w * 4 + c + 1;
#pragma unroll
            for (int rq = 0; rq < 4; rq++) mwpre[rq] = mrow[(long long)kblkn * NN + qbase + rq * 64 + lane];
        }
        asm volatile("s_waitcnt lgkmcnt(0)" ::: "memory");   // wave-private LDS writes visible
#pragma unroll 2
        for (int kk2 = 0; kk2 < 32; kk2++) {
            int idx = c * 64 + kk2 * 2;
#pragma unroll 2
            for (int par = 0; par < 2; par++) {
                int kk = kk2 * 2 + par;
                // grab this row's V from the double-buffer, immediately refill for row idx+2(+par)
                float4 v0, v1, v2, v3;
                if (par == 0) {
                    v0 = vb0[0]; v1 = vb0[1]; v2 = vb0[2]; v3 = vb0[3];
#pragma unroll
                    for (int i = 0; i < 4; i++) vb0[i] = vp4[(idx + 2) * 4 + i];   // <=2-row overread lands in next ws buffer
                } else {
                    v0 = vb1[0]; v1 = vb1[1]; v2 = vb1[2]; v3 = vb1[3];
#pragma unroll
                    for (int i = 0; i < 4; i++) vb1[i] = vp4[(idx + 3) * 4 + i];
                }
                const float4* kr = (const float4*)(sK + kk * 16);
                float4 k0 = kr[0], k1 = kr[1], k2 = kr[2], k3 = kr[3];
                float e[4];
#pragma unroll
                for (int rq = 0; rq < 4; rq++) {
                    float4 a0 = qf[rq][0], a1 = qf[rq][1], a2 = qf[rq][2], a3 = qf[rq][3];
                    float sA = a0.x * k0.x;
                    sA = fmaf(a0.y, k0.y, sA); sA = fmaf(a0.z, k0.z, sA); sA = fmaf(a0.w, k0.w, sA);
                    sA = fmaf(a1.x, k1.x, sA); sA = fmaf(a1.y, k1.y, sA); sA = fmaf(a1.z, k1.z, sA); sA = fmaf(a1.w, k1.w, sA);
                    float sB = a2.x * k2.x;
                    sB = fmaf(a2.y, k2.y, sB); sB = fmaf(a2.z, k2.z, sB); sB = fmaf(a2.w, k2.w, sB);
                    sB = fmaf(a3.x, k3.x, sB); sB = fmaf(a3.y, k3.y, sB); sB = fmaf(a3.z, k3.z, sB); sB = fmaf(a3.w, k3.w, sB);
                    float ee = __builtin_amdgcn_exp2f(sA + sB);     // softmax scale folded into Q
                    e[rq] = ((mw[rq] >> kk) & 1ULL) ? 0.f : ee;
                    lsum[rq] += e[rq];
                }
#pragma unroll
                for (int rq = 0; rq < 4; rq++) {
                    float ew = e[rq];
                    oacc[rq][0].x = fmaf(ew, v0.x, oacc[rq][0].x); oacc[rq][0].y = fmaf(ew, v0.y, oacc[rq][0].y);
                    oacc[rq][0].z = fmaf(ew, v0.z, oacc[rq][0].z); oacc[rq][0].w = fmaf(ew, v0.w, oacc[rq][0].w);
                    oacc[rq][1].x = fmaf(ew, v1.x, oacc[rq][1].x); oacc[rq][1].y = fmaf(ew, v1.y, oacc[rq][1].y);
                    oacc[rq][1].z = fmaf(ew, v1.z, oacc[rq][1].z); oacc[rq][1].w = fmaf(ew, v1.w, oacc[rq][1].w);
                    oacc[rq][2].x = fmaf(ew, v2.x, oacc[rq][2].x); oacc[rq][2].y = fmaf(ew, v2.y, oacc[rq][2].y);
                    oacc[rq][2].z = fmaf(ew, v2.z, oacc[rq][2].z); oacc[rq][2].w = fmaf(ew, v2.w, oacc[rq][2].w);
                    oacc[rq][3].x = fmaf(ew, v3.x, oacc[rq][3].x); oacc[rq][3].y = fmaf(ew, v3.y, oacc[rq][3].y);
                    oacc[rq][3].z = fmaf(ew, v3.z, oacc[rq][3].z); oacc[rq][3].w = fmaf(ew, v3.w, oacc[rq][3].w);
                }
            }
        }
    }
    __syncthreads();                                   // all K-staging reads done before overlay
#pragma unroll
    for (int rq = 0; rq < 4; rq++) {
        float* rp = smem + (((w * 4 + rq) * 64 + lane)) * 17;   // stride 17: 2 lanes/bank, free
#pragma unroll
        for (int j = 0; j < 4; j++) {
            rp[4 * j + 0] = oacc[rq][j].x; rp[4 * j + 1] = oacc[rq][j].y;
            rp[4 * j + 2] = oacc[rq][j].z; rp[4 * j + 3] = oacc[rq][j].w;
        }
        rp[16] = lsum[rq];
    }
    __syncthreads();
    if (w < 4) {
        int rq = w;
        float acc[DD]; float lt = 0.f;
#pragma unroll
        for (int d = 0; d < DD; d++) acc[d] = 0.f;
#pragma unroll
        for (int p = 0; p < 8; p++) {
            const float* pp = smem + (((p * 4 + rq) * 64 + lane)) * 17;
#pragma unroll
            for (int d = 0; d < DD; d++) acc[d] += pp[d];
            lt += pp[16];
        }
        float inv = 1.0f / lt;
        int q = qbase + rq * 64 + lane;
        float* op = O + (long long)(b * NN + q) * EE + h * DD;
        float4 r0 = {acc[0]*inv, acc[1]*inv, acc[2]*inv, acc[3]*inv};
        float4 r1 = {acc[4]*inv, acc[5]*inv, acc[6]*inv, acc[7]*inv};
        float4 r2 = {acc[8]*inv, acc[9]*inv, acc[10]*inv, acc[11]*inv};
        float4 r3 = {acc[12]*inv, acc[13]*inv, acc[14]*inv, acc[15]*inv};
        ((float4*)op)[0] = r0; ((float4*)op)[1] = r1; ((float4*)op)[2] = r2; ((float4*)op)[3] = r3;
    }
}

// ---------------- out-projection + ReLU (standalone, used for layer 1) ----------------
__global__ __launch_bounds__(256) void k_out(const float* __restrict__ X, const float* __restrict__ WO,
                                             const float* __restrict__ bO, float* __restrict__ Y) {
    int lane = threadIdx.x & 63, quarter = threadIdx.x >> 6;
    long long row = (long long)blockIdx.x * 64 + lane;
    float xr[64];
    const float4* xp = (const float4*)(X + row * 64);
#pragma unroll
    for (int i = 0; i < 16; i++) {
        float4 t = xp[i];
        xr[4 * i] = t.x; xr[4 * i + 1] = t.y; xr[4 * i + 2] = t.z; xr[4 * i + 3] = t.w;
    }
    for (int jq = 0; jq < 4; jq++) {
        int j = quarter * 16 + jq * 4;
        float4 acc = *(const float4*)(bO + j);
#pragma unroll
        for (int f = 0; f < 64; f++) {
            float4 w4 = *(const float4*)(WO + f * 64 + j);
            acc.x = fmaf(xr[f], w4.x, acc.x);
            acc.y = fmaf(xr[f], w4.y, acc.y);
            acc.z = fmaf(xr[f], w4.z, acc.z);
            acc.w = fmaf(xr[f], w4.w, acc.w);
        }
        acc.x = fmaxf(acc.x, 0.f); acc.y = fmaxf(acc.y, 0.f);
        acc.z = fmaxf(acc.z, 0.f); acc.w = fmaxf(acc.w, 0.f);
        *(float4*)(Y + row * 64 + j) = acc;
    }
}

// ---------------- fused: out-proj(L0)+ReLU -> QKV proj (L1), x1 never touches HBM ----------------
__global__ __launch_bounds__(256) void k_outqkv(const float* __restrict__ O, const float* __restrict__ WO,
                                                const float* __restrict__ bO,
                                                const float* __restrict__ CW, const float* __restrict__ bQ,
                                                float* __restrict__ Q, float* __restrict__ K, float* __restrict__ V) {
    __shared__ float xs[64 * 68];
    int lane = threadIdx.x & 63, quarter = threadIdx.x >> 6;
    long long row = (long long)blockIdx.x * 64 + lane;
    int b = (int)(row >> 11), n = (int)(row & (NN - 1));
    {
        float xr[64];
        const float4* xp = (const float4*)(O + row * 64);
#pragma unroll
        for (int i = 0; i < 16; i++) {
            float4 t = xp[i];
            xr[4 * i] = t.x; xr[4 * i + 1] = t.y; xr[4 * i + 2] = t.z; xr[4 * i + 3] = t.w;
        }
        for (int jq = 0; jq < 4; jq++) {
            int j = quarter * 16 + jq * 4;
            float4 acc = *(const float4*)(bO + j);
#pragma unroll
            for (int f = 0; f < 64; f++) {
                float4 w4 = *(const float4*)(WO + f * 64 + j);
                acc.x = fmaf(xr[f], w4.x, acc.x);
                acc.y = fmaf(xr[f], w4.y, acc.y);
                acc.z = fmaf(xr[f], w4.z, acc.z);
                acc.w = fmaf(xr[f], w4.w, acc.w);
            }
            acc.x = fmaxf(acc.x, 0.f); acc.y = fmaxf(acc.y, 0.f);
            acc.z = fmaxf(acc.z, 0.f); acc.w = fmaxf(acc.w, 0.f);
            *(float4*)(xs + lane * 68 + j) = acc;
        }
    }
    __syncthreads();
    {
        float xr[64];
        const float4* xp = (const float4*)(xs + lane * 68);
#pragma unroll
        for (int i = 0; i < 16; i++) {
            float4 t = xp[i];
            xr[4 * i] = t.x; xr[4 * i + 1] = t.y; xr[4 * i + 2] = t.z; xr[4 * i + 3] = t.w;
        }
        for (int jq = 0; jq < 12; jq++) {
            int j = quarter * 48 + jq * 4;
            float4 acc = *(const float4*)(bQ + j);
#pragma unroll
            for (int f = 0; f < 64; f++) {
                float4 w4 = *(const float4*)(CW + f * 192 + j);
                acc.x = fmaf(xr[f], w4.x, acc.x);
                acc.y = fmaf(xr[f], w4.y, acc.y);
                acc.z = fmaf(xr[f], w4.z, acc.z);
                acc.w = fmaf(xr[f], w4.w, acc.w);
            }
            int which = j >> 6, c = j & 63, h = c >> 4, d = c & 15;
            float* dst = (which == 0) ? Q : ((which == 1) ? K : V);
            *(float4*)(dst + (((long long)(b * HH + h) * NN + n) * DD + d)) = acc;
        }
    }
}

// ---------------- fused 3-layer MLP head v2: 2-pass stage2, padded LDS ----------------
__global__ __launch_bounds__(128) void k_head(const float* __restrict__ X,
                                              const float* __restrict__ w1, const float* __restrict__ b1,
                                              const float* __restrict__ w2, const float* __restrict__ b2,
                                              const float* __restrict__ w3, const float* __restrict__ b3,
                                              float* __restrict__ out) {
    __shared__ float Xs[16 * 64];
    __shared__ float H1[16 * 132];
    __shared__ float H2[16 * 132];
    int tid = threadIdx.x;
    long long row0 = (long long)blockIdx.x * 16;
    {
        const float4* src = (const float4*)(X + row0 * 64);
        float4* dst = (float4*)Xs;
        dst[tid] = src[tid];
        dst[tid + 128] = src[tid + 128];
    }
    __syncthreads();
    {
        float wr[64];
#pragma unroll
        for (int f = 0; f < 64; f++) wr[f] = w1[f * 128 + tid];
        float bb = b1[tid];
        for (int r = 0; r < 16; r++) {
            const float4* x4 = (const float4*)(Xs + r * 64);
            float a0 = bb, a1 = 0.f, a2 = 0.f, a3 = 0.f;
#pragma unroll
            for (int fq = 0; fq < 16; fq++) {
                float4 xv = x4[fq];
                a0 = fmaf(xv.x, wr[4 * fq], a0);
                a1 = fmaf(xv.y, wr[4 * fq + 1], a1);
                a2 = fmaf(xv.z, wr[4 * fq + 2], a2);
                a3 = fmaf(xv.w, wr[4 * fq + 3], a3);
            }
            H1[r * 132 + tid] = fmaxf((a0 + a1) + (a2 + a3), 0.f);
        }
    }
    __syncthreads();
    {
        float acc2[16];
        float bb2 = b2[tid];
#pragma unroll
        for (int r = 0; r < 16; r++) acc2[r] = bb2;
#pragma unroll
        for (int p = 0; p < 2; p++) {
            float wr2[64];
#pragma unroll
            for (int i = 0; i < 64; i++) wr2[i] = w2[(p * 64 + i) * 128 + tid];
            for (int r = 0; r < 16; r++) {
                const float4* h4 = (const float4*)(H1 + r * 132 + p * 64);
                float a0 = 0.f, a1 = 0.f, a2 = 0.f, a3 = 0.f;
#pragma unroll
                for (int fq = 0; fq < 16; fq++) {
                    float4 xv = h4[fq];
                    a0 = fmaf(xv.x, wr2[4 * fq], a0);
                    a1 = fmaf(xv.y, wr2[4 * fq + 1], a1);
                    a2 = fmaf(xv.z, wr2[4 * fq + 2], a2);
                    a3 = fmaf(xv.w, wr2[4 * fq + 3], a3);
                }
                acc2[r] += (a0 + a1) + (a2 + a3);
            }
        }
#pragma unroll
        for (int r = 0; r < 16; r++) H2[r * 132 + tid] = fmaxf(acc2[r], 0.f);
    }
    __syncthreads();
    if (tid < 64) {
        int r = tid >> 2, a = tid & 3;
        float acc = b3[a];
        for (int f = 0; f < 128; f++) acc = fmaf(H2[r * 132 + f], w3[f * 4 + a], acc);
        out[(row0 + r) * 4 + a] = acc;
    }
}

extern "C" void kernel_launch(void* const* d_in, const int* in_sizes, int n_in,
                              void* d_out, int out_size, void* d_ws, size_t ws_size,
                              hipStream_t stream) {
    const float* nf = (const float*)d_in[0];
    const float* adj = (const float*)d_in[1];
    const float* l0[9]; for (int i = 0; i < 9; i++) l0[i] = (const float*)d_in[2 + i];
    const float* l1[9]; for (int i = 0; i < 9; i++) l1[i] = (const float*)d_in[11 + i];
    const float* hw1 = (const float*)d_in[20]; const float* hb1 = (const float*)d_in[21];
    const float* hw2 = (const float*)d_in[22]; const float* hb2 = (const float*)d_in[23];
    const float* hw3 = (const float*)d_in[24]; const float* hb3 = (const float*)d_in[25];
    float* out = (float*)d_out;

    char* ws = (char*)d_ws;
    size_t off = 0;
    auto alloc = [&](size_t bytes) -> void* {
        void* p = ws + off;
        off = (off + bytes + 255) & ~(size_t)255;
        return p;
    };
    unsigned long long* mbT = (unsigned long long*)alloc((size_t)BB * NN * NN / 8);
    float* Q = (float*)alloc((size_t)BB * HH * NN * DD * 4);
    float* K = (float*)alloc((size_t)BB * HH * NN * DD * 4);
    float* V = (float*)alloc((size_t)BB * HH * NN * DD * 4);
    float* O = (float*)alloc((size_t)BB * NN * EE * 4);
    float* x2 = (float*)alloc((size_t)BB * NN * EE * 4);
    float* CW0 = (float*)alloc(16 * 192 * 4);
    float* CW1 = (float*)alloc(64 * 192 * 4);
    float* WO0 = (float*)alloc(64 * 64 * 4);
    float* WO1 = (float*)alloc(64 * 64 * 4);
    float* bO0 = (float*)alloc(64 * 4);
    float* bO1 = (float*)alloc(64 * 4);
    float* bQ0 = (float*)alloc(192 * 4);
    float* bQ1 = (float*)alloc(192 * 4);

    k_mask<<<4096, 256, 0, stream>>>(adj, mbT);
    k_wcomb<<<dim3(65, 2), 256, 0, stream>>>(
        l0[0], l0[1], l0[2], l0[3], l0[4], l0[5], l0[6], l0[7], l0[8],
        l1[0], l1[1], l1[2], l1[3], l1[4], l1[5], l1[6], l1[7], l1[8],
        CW0, WO0, bO0, bQ0, CW1, WO1, bO1, bQ1);

    // layer 0 (feature scale folded into CW0)
    k_qkv<16><<<BB * NN / 64, 256, 0, stream>>>(nf, CW0, bQ0, Q, K, V);
    k_attn<<<dim3(NN / 256, HH, BB), 512, 0, stream>>>(Q, K, V, mbT, O);
    // fused: out-proj L0 + QKV proj L1
    k_outqkv<<<BB * NN / 64, 256, 0, stream>>>(O, WO0, bO0, CW1, bQ1, Q, K, V);
    k_attn<<<dim3(NN / 256, HH, BB), 512, 0, stream>>>(Q, K, V, mbT, O);
    k_out<<<BB * NN / 64, 256, 0, stream>>>(O, WO1, bO1, x2);
    // head
    k_head<<<BB * NN / 16, 128, 0, stream>>>(x2, hw1, hb1, hw2, hb2, hw3, hb3, out);
}